// Round 12
// baseline (116.062 us; speedup 1.0000x reference)
//
#include <hip/hip_runtime.h>
#include <hip/hip_bf16.h>
#include <cstdint>

#define K_V_C   1.05f
#define G_DIFF  4.0e-4f   // G_MAX - G_MIN
#define KP4     4608      // k = 4*j + level (level 3 = zero pad), j padded to 1152

typedef __attribute__((ext_vector_type(8))) short short8;
typedef __attribute__((ext_vector_type(4))) float f32x4;

// I_REF rows 1..3 (row 0 is all zeros)
__device__ __constant__ float c_I1[9] = {-0.00015f,-0.00011f,-7e-05f,-3e-05f,0.f,3e-05f,7e-05f,0.00011f,0.00015f};
__device__ __constant__ float c_I2[9] = {-0.0005f,-0.00035f,-0.00022f,-9e-05f,0.f,9e-05f,0.00022f,0.00035f,0.0005f};
__device__ __constant__ float c_I3[9] = {-0.0009f,-0.0006f,-0.00037f,-0.00015f,0.f,0.00015f,0.00037f,0.0006f,0.0009f};

__device__ inline unsigned short f2bf(float f) {   // fp32 -> bf16 RNE
  unsigned int u = __float_as_uint(f);
  u += 0x7FFFu + ((u >> 16) & 1u);
  return (unsigned short)(u >> 16);
}

__device__ inline void interp3(float v, float& u1, float& u2, float& u3) {
  const float sf = v * 3.3333333333333335f + 4.0f;   // (v+1.2)/0.3
  float fs = floorf(sf);
  fs = fminf(fmaxf(fs, 0.f), 7.f);
  const int   s  = (int)fs;
  const float fr = fminf(fmaxf(sf - fs, 0.f), 1.f);
  u1 = fmaf(fr, c_I1[s+1] - c_I1[s], c_I1[s]);
  u2 = fmaf(fr, c_I2[s+1] - c_I2[s], c_I2[s]);
  u3 = fmaf(fr, c_I3[s+1] - c_I3[s], c_I3[s]);
}

// branch-free coeff3: clamped ramps, differences, sign OR'd in.
__device__ inline void coeff3f(float g, float& c1, float& c2, float& c3) {
  const float    ga = fabsf(g);
  const unsigned sb = __float_as_uint(g) & 0x80000000u;
  const float t1 = fminf(ga * 1e4f, 1.f);
  const float t2 = fminf(fmaxf((ga - 1e-4f) * 5e3f, 0.f), 1.f);
  const float t3 = fmaxf((ga - 3e-4f) * 5e3f, 0.f);
  c1 = __uint_as_float(__float_as_uint(t1 - t2) | sb);
  c2 = __uint_as_float(__float_as_uint(t2 - t3) | sb);
  c3 = __uint_as_float(__float_as_uint(t3) | sb);
}

__device__ inline void coeff3(float g, float& c1, float& c2, float& c3) {
  const float ga  = fabsf(g);
  const float sgn = (g > 0.f) ? 1.f : ((g < 0.f) ? -1.f : 0.f);
  const int   idx = (ga >= 3e-4f) ? 2 : ((ga >= 1e-4f) ? 1 : 0);
  const float g0   = (idx == 0) ? 0.f : ((idx == 1) ? 1e-4f : 3e-4f);
  const float invd = (idx == 0) ? 1e4f : 5e3f;
  const float t    = (ga - g0) * invd;
  const float clo = sgn * (1.f - t), chi = sgn * t;
  c1 = (idx == 0) ? chi : ((idx == 1) ? clo : 0.f);
  c2 = (idx == 1) ? chi : ((idx == 2) ? clo : 0.f);
  c3 = (idx == 2) ? chi : 0.f;
}

// ---------------------------------------------------------------------------
// MONO kernel: 512 blocks x 512 thr (2 blocks/CU, all co-resident).
//   phase 1: per-block maxabs partial (all) + prep U (blocks 0..71)
//   flag barrier (device-scope counter, s_sleep spin)
//   phase 2: r11's GEMM (split-K x8, LDS w-panel [1024 j][16 m], 18 steps)
// ---------------------------------------------------------------------------
__global__ __launch_bounds__(512, 4) void mono_kernel(
    const float* __restrict__ x, const float* __restrict__ w,
    const float* __restrict__ bias, unsigned int* __restrict__ counter,
    float* __restrict__ partials, unsigned short* __restrict__ Ub,
    float* __restrict__ out) {
  __shared__ __align__(16) float lds[16384];   // 64 KB exactly
  const int t = threadIdx.x, bid = blockIdx.x;
  const int wv = t >> 6, lane = t & 63, la = lane & 15, kg = lane >> 4;

  // ---- phase 1a: maxabs partial (one float4 of w per thread) ----
  {
    const int i = bid * 512 + t;               // covers all 262144 f4 of w
    const float4 v = ((const float4*)w)[i];
    float m = fmaxf(fmaxf(fabsf(v.x), fabsf(v.y)), fmaxf(fabsf(v.z), fabsf(v.w)));
    if (bid == 0 && t < 256) {
      const float4 bv4 = ((const float4*)bias)[t];
      m = fmaxf(m, fmaxf(fmaxf(fabsf(bv4.x), fabsf(bv4.y)),
                         fmaxf(fabsf(bv4.z), fabsf(bv4.w))));
    }
    #pragma unroll
    for (int o = 32; o > 0; o >>= 1) m = fmaxf(m, __shfl_down(m, o, 64));
    if (lane == 0) lds[wv] = m;
    __syncthreads();
    if (t == 0) {
      float r = lds[0];
      #pragma unroll
      for (int i2 = 1; i2 < 8; ++i2) r = fmaxf(r, lds[i2]);
      partials[bid] = r;
    }
  }

  // ---- phase 1b: prep U bf16 [128][KP4] (blocks 0..71; x-only, no maxw) ----
  if (bid < 72) {
    const int idx = bid * 512 + t;             // 36864 = 128 b x 288 j4-groups
    const int b = idx / 288, j4 = idx - b * 288;
    ushort4 o0 = make_ushort4(0,0,0,0), o1 = o0, o2 = o0, o3 = o0;
    if (j4 < 256) {
      const float4 xv = ((const float4*)x)[b * 256 + j4];
      float u1, u2, u3;
      interp3(K_V_C * xv.x, u1, u2, u3); o0 = make_ushort4(f2bf(u1), f2bf(u2), f2bf(u3), 0);
      interp3(K_V_C * xv.y, u1, u2, u3); o1 = make_ushort4(f2bf(u1), f2bf(u2), f2bf(u3), 0);
      interp3(K_V_C * xv.z, u1, u2, u3); o2 = make_ushort4(f2bf(u1), f2bf(u2), f2bf(u3), 0);
      interp3(K_V_C * xv.w, u1, u2, u3); o3 = make_ushort4(f2bf(u1), f2bf(u2), f2bf(u3), 0);
    } else if (j4 == 256) {                    // j = 1024: ones/bias column
      float u1, u2, u3;
      interp3(K_V_C, u1, u2, u3);
      o0 = make_ushort4(f2bf(u1), f2bf(u2), f2bf(u3), 0);
    }
    ushort4* dst = (ushort4*)(Ub + (size_t)b * KP4 + j4 * 16);
    dst[0] = o0; dst[1] = o1; dst[2] = o2; dst[3] = o3;
  }

  // ---- signal: this block's partial + U slice are globally visible ----
  __syncthreads();
  if (t == 0) { __threadfence(); atomicAdd(counter, 1u); }

  // ---- stage w-panel (independent of phase 1; hides under barrier wait) ----
  const int b0 = (bid >> 6) * 16;
  const int n0 = (bid & 63) * 16;
  const int m  = n0 + la;
  #pragma unroll
  for (int i = 0; i < 8; ++i) {
    const int idx = i * 512 + t;               // 4096 float4 of the panel
    const int row = idx >> 2, c4 = idx & 3;    // row = j
    const float4 v = *(const float4*)(w + (size_t)row * 1024 + n0 + c4 * 4);
    *(float4*)&lds[row * 16 + c4 * 4] = v;
  }
  const float bv = bias[m];

  // ---- flag barrier: wait for all 512 blocks ----
  if (t == 0) {
    while (atomicAdd(counter, 0u) < 512u) __builtin_amdgcn_s_sleep(8);
  }
  __syncthreads();
  __threadfence();                             // acquire: partials/Ub visible

  // ---- maxw from 512 partials ----
  float mx = 0.f;
  #pragma unroll
  for (int i = 0; i < 2; ++i) {
    const float4 p = ((const float4*)partials)[lane + i * 64];
    mx = fmaxf(mx, fmaxf(fmaxf(p.x, p.y), fmaxf(p.z, p.w)));
  }
  #pragma unroll
  for (int o = 1; o < 64; o <<= 1) mx = fmaxf(mx, __shfl_xor(mx, o, 64));
  const float maxw = mx;
  const float kG   = G_DIFF / maxw;

  // ---- 18-step branch-free MFMA loop (wave = k-slice of 576 = 144 j) ----
  const unsigned short* Ap = Ub + (size_t)(b0 + la) * KP4 + wv * 576 + kg * 8;
  const int jb = wv * 144 + kg * 2;
  f32x4 acc = {0.f, 0.f, 0.f, 0.f};
  #pragma unroll 6
  for (int ks = 0; ks < 18; ++ks) {
    const short8 a = *(const short8*)(Ap + ks * 32);
    const int j0 = jb + ks * 8;                // this lane's two j's: j0, j0+1
    const float ra = lds[min(j0, 1023) * 16 + la];
    const float rb = lds[min(j0 + 1, 1023) * 16 + la];
    const float wa = (j0 < 1024) ? ra : ((j0 == 1024) ? bv : 0.f);
    const float wb = (j0 + 1 < 1024) ? rb : ((j0 + 1 == 1024) ? bv : 0.f);
    float a1, a2, a3, b1, b2, b3;
    coeff3f(kG * wa, a1, a2, a3);
    coeff3f(kG * wb, b1, b2, b3);
    union { __hip_bfloat162 h[4]; short8 s; } bf;
    bf.h[0] = __float22bfloat162_rn(make_float2(a1, a2));
    bf.h[1] = __float22bfloat162_rn(make_float2(a3, 0.f));
    bf.h[2] = __float22bfloat162_rn(make_float2(b1, b2));
    bf.h[3] = __float22bfloat162_rn(make_float2(b3, 0.f));
    acc = __builtin_amdgcn_mfma_f32_16x16x32_bf16(a, bf.s, acc, 0, 0, 0);
  }

  // ---- cross-wave K-reduce (P aliases the w-panel) + fused scale ----
  __syncthreads();                             // all waves done reading panel
  *(float4*)&lds[wv * 256 + lane * 4] = make_float4(acc[0], acc[1], acc[2], acc[3]);
  __syncthreads();
  if (t < 256) {
    float s = 0.f;
    #pragma unroll
    for (int ww = 0; ww < 8; ++ww) s += lds[ww * 256 + t];
    const int l2 = t >> 2, ai = t & 3;         // D: col = lane&15, row = kg*4+r
    const int row = b0 + ((l2 >> 4) << 2) + ai;
    const int col = n0 + (l2 & 15);
    out[(size_t)row * 1024 + col] = s * (maxw * (1.0f / (K_V_C * G_DIFF)));
  }
}

// ---------------------------------------------------------------------------
// Fallback (tiny ws): atomic-based path, needs only 4 bytes of ws.
// ---------------------------------------------------------------------------
__global__ __launch_bounds__(256) void maxabs_atomic_kernel(
    const float* __restrict__ w, const float* __restrict__ b,
    unsigned int* __restrict__ wsmax) {
  const int NW4 = 262144, NB4 = 256;
  float m = 0.f;
  for (int i = blockIdx.x * blockDim.x + threadIdx.x; i < NW4 + NB4;
       i += gridDim.x * blockDim.x) {
    float4 v = (i < NW4) ? ((const float4*)w)[i] : ((const float4*)b)[i - NW4];
    m = fmaxf(m, fmaxf(fmaxf(fabsf(v.x), fabsf(v.y)),
                       fmaxf(fabsf(v.z), fabsf(v.w))));
  }
  #pragma unroll
  for (int o = 32; o > 0; o >>= 1) m = fmaxf(m, __shfl_down(m, o, 64));
  __shared__ float red[4];
  if ((threadIdx.x & 63) == 0) red[threadIdx.x >> 6] = m;
  __syncthreads();
  if (threadIdx.x == 0)
    atomicMax(wsmax, __float_as_uint(fmaxf(fmaxf(red[0], red[1]),
                                           fmaxf(red[2], red[3]))));
}

__global__ __launch_bounds__(256) void memristor_atomic_kernel(
    const float* __restrict__ x, const float* __restrict__ w,
    const float* __restrict__ bias, const unsigned int* __restrict__ wsmax,
    float* __restrict__ out) {
  __shared__ float4 U[2048];
  const int tid = threadIdx.x;
  const float maxw  = __uint_as_float(*wsmax);
  const float kG    = G_DIFF / maxw;
  const float scale = maxw * (1.0f / (K_V_C * G_DIFF));
  const int mq = tid & 15, bg = tid >> 4;
  const int m0 = blockIdx.x * 64 + mq * 4;
  const int swz = bg & 7;
  float acc[4][8];
  #pragma unroll
  for (int a = 0; a < 4; ++a)
    #pragma unroll
    for (int c = 0; c < 8; ++c) acc[a][c] = 0.f;
  for (int sc = blockIdx.y; sc < 65; sc += 16) {
    const int j0 = sc * 16;
    const int nj = min(16, 1025 - j0);
    __syncthreads();
    #pragma unroll
    for (int k = 0; k < 8; ++k) {
      const int e = k * 256 + tid;
      const int jl = e & 15, b = e >> 4;
      const int jg = j0 + jl;
      if (jg <= 1024) {
        const float v = (jg < 1024) ? K_V_C * x[b * 1024 + jg] : K_V_C;
        float u1, u2, u3;
        interp3(v, u1, u2, u3);
        U[b * 16 + (jl ^ ((b >> 3) & 7))] = make_float4(0.f, u1, u2, u3);
      }
    }
    __syncthreads();
    for (int jl = 0; jl < nj; ++jl) {
      const int jg = j0 + jl;
      const float4 wv = (jg < 1024) ? *(const float4*)(w + jg * 1024 + m0)
                                    : *(const float4*)(bias + m0);
      const float warr[4] = {wv.x, wv.y, wv.z, wv.w};
      float c1[4], c2[4], c3[4];
      #pragma unroll
      for (int mi = 0; mi < 4; ++mi) coeff3(kG * warr[mi], c1[mi], c2[mi], c3[mi]);
      const int base = bg * 128 + (jl ^ swz);
      #pragma unroll
      for (int bb = 0; bb < 8; ++bb) {
        const float4 u = U[base + bb * 16];
        #pragma unroll
        for (int mi = 0; mi < 4; ++mi)
          acc[mi][bb] = fmaf(c1[mi], u.y, fmaf(c2[mi], u.z, fmaf(c3[mi], u.w, acc[mi][bb])));
      }
    }
  }
  #pragma unroll
  for (int bb = 0; bb < 8; ++bb) {
    const int b = bg * 8 + bb;
    #pragma unroll
    for (int mi = 0; mi < 4; ++mi)
      atomicAdd(&out[b * 1024 + m0 + mi], acc[mi][bb] * scale);
  }
}

// ---------------------------------------------------------------------------
extern "C" void kernel_launch(void* const* d_in, const int* in_sizes, int n_in,
                              void* d_out, int out_size, void* d_ws, size_t ws_size,
                              hipStream_t stream) {
  const float* x = (const float*)d_in[0];   // (128, 1024)
  const float* w = (const float*)d_in[1];   // (1024, 1024)
  const float* b = (const float*)d_in[2];   // (1024,)
  float* out = (float*)d_out;               // (128, 1024) fp32

  unsigned int*   counter  = (unsigned int*)d_ws;
  float*          partials = (float*)((char*)d_ws + 128);        // 512 f32
  unsigned short* Ub = (unsigned short*)((char*)d_ws + 8192);    // 1,179,648 B
  const size_t need = 8192 + (size_t)128 * KP4 * 2;              // ~1.13 MB

  if (ws_size >= need) {
    hipMemsetAsync(counter, 0, 4, stream);
    mono_kernel<<<512, 512, 0, stream>>>(x, w, b, counter, partials, Ub, out);
  } else {                                 // fallback: tiny ws, atomic path
    unsigned int* wsmax = (unsigned int*)d_ws;
    hipMemsetAsync(wsmax, 0, 4, stream);
    maxabs_atomic_kernel<<<256, 256, 0, stream>>>(w, b, wsmax);
    hipMemsetAsync(out, 0, (size_t)out_size * sizeof(float), stream);
    dim3 grid(16, 16);
    memristor_atomic_kernel<<<grid, 256, 0, stream>>>(x, w, b, wsmax, out);
  }
}

// Round 13
// 115.382 us; speedup vs baseline: 1.0059x; 1.0059x over previous
//
#include <hip/hip_runtime.h>
#include <hip/hip_bf16.h>
#include <cstdint>

#define K_V_C   1.05f
#define G_DIFF  4.0e-4f   // G_MAX - G_MIN
#define KP4     4608      // k = 4*j + level (level 3 = zero pad), j padded to 1152

typedef __attribute__((ext_vector_type(8))) short short8;
typedef __attribute__((ext_vector_type(4))) float f32x4;

// I_REF rows 1..3 (row 0 is all zeros)
__device__ __constant__ float c_I1[9] = {-0.00015f,-0.00011f,-7e-05f,-3e-05f,0.f,3e-05f,7e-05f,0.00011f,0.00015f};
__device__ __constant__ float c_I2[9] = {-0.0005f,-0.00035f,-0.00022f,-9e-05f,0.f,9e-05f,0.00022f,0.00035f,0.0005f};
__device__ __constant__ float c_I3[9] = {-0.0009f,-0.0006f,-0.00037f,-0.00015f,0.f,0.00015f,0.00037f,0.0006f,0.0009f};

__device__ inline unsigned short f2bf(float f) {   // fp32 -> bf16 RNE
  unsigned int u = __float_as_uint(f);
  u += 0x7FFFu + ((u >> 16) & 1u);
  return (unsigned short)(u >> 16);
}

__device__ inline void interp3(float v, float& u1, float& u2, float& u3) {
  const float sf = v * 3.3333333333333335f + 4.0f;   // (v+1.2)/0.3
  float fs = floorf(sf);
  fs = fminf(fmaxf(fs, 0.f), 7.f);
  const int   s  = (int)fs;
  const float fr = fminf(fmaxf(sf - fs, 0.f), 1.f);
  u1 = fmaf(fr, c_I1[s+1] - c_I1[s], c_I1[s]);
  u2 = fmaf(fr, c_I2[s+1] - c_I2[s], c_I2[s]);
  u3 = fmaf(fr, c_I3[s+1] - c_I3[s], c_I3[s]);
}

// branch-free coeff3: clamped ramps, differences, sign OR'd in.
__device__ inline void coeff3f(float g, float& c1, float& c2, float& c3) {
  const float    ga = fabsf(g);
  const unsigned sb = __float_as_uint(g) & 0x80000000u;
  const float t1 = fminf(ga * 1e4f, 1.f);
  const float t2 = fminf(fmaxf((ga - 1e-4f) * 5e3f, 0.f), 1.f);
  const float t3 = fmaxf((ga - 3e-4f) * 5e3f, 0.f);
  c1 = __uint_as_float(__float_as_uint(t1 - t2) | sb);
  c2 = __uint_as_float(__float_as_uint(t2 - t3) | sb);
  c3 = __uint_as_float(__float_as_uint(t3) | sb);
}

__device__ inline void coeff3(float g, float& c1, float& c2, float& c3) {
  const float ga  = fabsf(g);
  const float sgn = (g > 0.f) ? 1.f : ((g < 0.f) ? -1.f : 0.f);
  const int   idx = (ga >= 3e-4f) ? 2 : ((ga >= 1e-4f) ? 1 : 0);
  const float g0   = (idx == 0) ? 0.f : ((idx == 1) ? 1e-4f : 3e-4f);
  const float invd = (idx == 0) ? 1e4f : 5e3f;
  const float t    = (ga - g0) * invd;
  const float clo = sgn * (1.f - t), chi = sgn * t;
  c1 = (idx == 0) ? chi : ((idx == 1) ? clo : 0.f);
  c2 = (idx == 1) ? chi : ((idx == 2) ? clo : 0.f);
  c3 = (idx == 2) ? chi : 0.f;
}

// ---------------------------------------------------------------------------
// MONO kernel: 512 blocks x 512 thr (2 blocks/CU, all co-resident).
//   phase 1: per-block maxabs partial (all) + prep U (blocks 0..71)
//   flag barrier: signal = one atomicAdd per block; wait = SPIN ON ATOMIC
//   LOAD (agent scope) — NOT an RMW (r12's atomicAdd(p,0) storm cost ~100us).
//   phase 2: r11's GEMM (split-K x8, LDS w-panel [1024 j][16 m], 18 steps)
// ---------------------------------------------------------------------------
__global__ __launch_bounds__(512, 4) void mono_kernel(
    const float* __restrict__ x, const float* __restrict__ w,
    const float* __restrict__ bias, unsigned int* __restrict__ counter,
    float* __restrict__ partials, unsigned short* __restrict__ Ub,
    float* __restrict__ out) {
  __shared__ __align__(16) float lds[16384];   // 64 KB exactly
  const int t = threadIdx.x, bid = blockIdx.x;
  const int wv = t >> 6, lane = t & 63, la = lane & 15, kg = lane >> 4;

  // ---- phase 1a: maxabs partial (one float4 of w per thread) ----
  {
    const int i = bid * 512 + t;               // covers all 262144 f4 of w
    const float4 v = ((const float4*)w)[i];
    float m = fmaxf(fmaxf(fabsf(v.x), fabsf(v.y)), fmaxf(fabsf(v.z), fabsf(v.w)));
    if (bid == 0 && t < 256) {
      const float4 bv4 = ((const float4*)bias)[t];
      m = fmaxf(m, fmaxf(fmaxf(fabsf(bv4.x), fabsf(bv4.y)),
                         fmaxf(fabsf(bv4.z), fabsf(bv4.w))));
    }
    #pragma unroll
    for (int o = 32; o > 0; o >>= 1) m = fmaxf(m, __shfl_down(m, o, 64));
    if (lane == 0) lds[wv] = m;
    __syncthreads();
    if (t == 0) {
      float r = lds[0];
      #pragma unroll
      for (int i2 = 1; i2 < 8; ++i2) r = fmaxf(r, lds[i2]);
      partials[bid] = r;
    }
  }

  // ---- phase 1b: prep U bf16 [128][KP4] (blocks 0..71; x-only, no maxw) ----
  if (bid < 72) {
    const int idx = bid * 512 + t;             // 36864 = 128 b x 288 j4-groups
    const int b = idx / 288, j4 = idx - b * 288;
    ushort4 o0 = make_ushort4(0,0,0,0), o1 = o0, o2 = o0, o3 = o0;
    if (j4 < 256) {
      const float4 xv = ((const float4*)x)[b * 256 + j4];
      float u1, u2, u3;
      interp3(K_V_C * xv.x, u1, u2, u3); o0 = make_ushort4(f2bf(u1), f2bf(u2), f2bf(u3), 0);
      interp3(K_V_C * xv.y, u1, u2, u3); o1 = make_ushort4(f2bf(u1), f2bf(u2), f2bf(u3), 0);
      interp3(K_V_C * xv.z, u1, u2, u3); o2 = make_ushort4(f2bf(u1), f2bf(u2), f2bf(u3), 0);
      interp3(K_V_C * xv.w, u1, u2, u3); o3 = make_ushort4(f2bf(u1), f2bf(u2), f2bf(u3), 0);
    } else if (j4 == 256) {                    // j = 1024: ones/bias column
      float u1, u2, u3;
      interp3(K_V_C, u1, u2, u3);
      o0 = make_ushort4(f2bf(u1), f2bf(u2), f2bf(u3), 0);
    }
    ushort4* dst = (ushort4*)(Ub + (size_t)b * KP4 + j4 * 16);
    dst[0] = o0; dst[1] = o1; dst[2] = o2; dst[3] = o3;
  }

  // ---- signal: this block's partial + U slice are globally visible ----
  __syncthreads();
  if (t == 0) { __threadfence(); atomicAdd(counter, 1u); }

  // ---- stage w-panel (independent of phase 1; hides under barrier wait) ----
  const int b0 = (bid >> 6) * 16;
  const int n0 = (bid & 63) * 16;
  const int m  = n0 + la;
  #pragma unroll
  for (int i = 0; i < 8; ++i) {
    const int idx = i * 512 + t;               // 4096 float4 of the panel
    const int row = idx >> 2, c4 = idx & 3;    // row = j
    const float4 v = *(const float4*)(w + (size_t)row * 1024 + n0 + c4 * 4);
    *(float4*)&lds[row * 16 + c4 * 4] = v;
  }
  const float bv = bias[m];

  // ---- flag barrier: spin on coherent LOAD (no RMW), s_sleep backoff ----
  if (t == 0) {
    while (__hip_atomic_load(counter, __ATOMIC_RELAXED,
                             __HIP_MEMORY_SCOPE_AGENT) < 512u)
      __builtin_amdgcn_s_sleep(16);
  }
  __syncthreads();
  __threadfence();                             // acquire: partials/Ub visible

  // ---- maxw from 512 partials ----
  float mx = 0.f;
  #pragma unroll
  for (int i = 0; i < 2; ++i) {
    const float4 p = ((const float4*)partials)[lane + i * 64];
    mx = fmaxf(mx, fmaxf(fmaxf(p.x, p.y), fmaxf(p.z, p.w)));
  }
  #pragma unroll
  for (int o = 1; o < 64; o <<= 1) mx = fmaxf(mx, __shfl_xor(mx, o, 64));
  const float maxw = mx;
  const float kG   = G_DIFF / maxw;

  // ---- 18-step branch-free MFMA loop (wave = k-slice of 576 = 144 j) ----
  const unsigned short* Ap = Ub + (size_t)(b0 + la) * KP4 + wv * 576 + kg * 8;
  const int jb = wv * 144 + kg * 2;
  f32x4 acc = {0.f, 0.f, 0.f, 0.f};
  #pragma unroll 6
  for (int ks = 0; ks < 18; ++ks) {
    const short8 a = *(const short8*)(Ap + ks * 32);
    const int j0 = jb + ks * 8;                // this lane's two j's: j0, j0+1
    const float ra = lds[min(j0, 1023) * 16 + la];
    const float rb = lds[min(j0 + 1, 1023) * 16 + la];
    const float wa = (j0 < 1024) ? ra : ((j0 == 1024) ? bv : 0.f);
    const float wb = (j0 + 1 < 1024) ? rb : ((j0 + 1 == 1024) ? bv : 0.f);
    float a1, a2, a3, b1, b2, b3;
    coeff3f(kG * wa, a1, a2, a3);
    coeff3f(kG * wb, b1, b2, b3);
    union { __hip_bfloat162 h[4]; short8 s; } bf;
    bf.h[0] = __float22bfloat162_rn(make_float2(a1, a2));
    bf.h[1] = __float22bfloat162_rn(make_float2(a3, 0.f));
    bf.h[2] = __float22bfloat162_rn(make_float2(b1, b2));
    bf.h[3] = __float22bfloat162_rn(make_float2(b3, 0.f));
    acc = __builtin_amdgcn_mfma_f32_16x16x32_bf16(a, bf.s, acc, 0, 0, 0);
  }

  // ---- cross-wave K-reduce (P aliases the w-panel) + fused scale ----
  __syncthreads();                             // all waves done reading panel
  *(float4*)&lds[wv * 256 + lane * 4] = make_float4(acc[0], acc[1], acc[2], acc[3]);
  __syncthreads();
  if (t < 256) {
    float s = 0.f;
    #pragma unroll
    for (int ww = 0; ww < 8; ++ww) s += lds[ww * 256 + t];
    const int l2 = t >> 2, ai = t & 3;         // D: col = lane&15, row = kg*4+r
    const int row = b0 + ((l2 >> 4) << 2) + ai;
    const int col = n0 + (l2 & 15);
    out[(size_t)row * 1024 + col] = s * (maxw * (1.0f / (K_V_C * G_DIFF)));
  }
}

// ---------------------------------------------------------------------------
// Fallback (tiny ws): atomic-based path, needs only 4 bytes of ws.
// ---------------------------------------------------------------------------
__global__ __launch_bounds__(256) void maxabs_atomic_kernel(
    const float* __restrict__ w, const float* __restrict__ b,
    unsigned int* __restrict__ wsmax) {
  const int NW4 = 262144, NB4 = 256;
  float m = 0.f;
  for (int i = blockIdx.x * blockDim.x + threadIdx.x; i < NW4 + NB4;
       i += gridDim.x * blockDim.x) {
    float4 v = (i < NW4) ? ((const float4*)w)[i] : ((const float4*)b)[i - NW4];
    m = fmaxf(m, fmaxf(fmaxf(fabsf(v.x), fabsf(v.y)),
                       fmaxf(fabsf(v.z), fabsf(v.w))));
  }
  #pragma unroll
  for (int o = 32; o > 0; o >>= 1) m = fmaxf(m, __shfl_down(m, o, 64));
  __shared__ float red[4];
  if ((threadIdx.x & 63) == 0) red[threadIdx.x >> 6] = m;
  __syncthreads();
  if (threadIdx.x == 0)
    atomicMax(wsmax, __float_as_uint(fmaxf(fmaxf(red[0], red[1]),
                                           fmaxf(red[2], red[3]))));
}

__global__ __launch_bounds__(256) void memristor_atomic_kernel(
    const float* __restrict__ x, const float* __restrict__ w,
    const float* __restrict__ bias, const unsigned int* __restrict__ wsmax,
    float* __restrict__ out) {
  __shared__ float4 U[2048];
  const int tid = threadIdx.x;
  const float maxw  = __uint_as_float(*wsmax);
  const float kG    = G_DIFF / maxw;
  const float scale = maxw * (1.0f / (K_V_C * G_DIFF));
  const int mq = tid & 15, bg = tid >> 4;
  const int m0 = blockIdx.x * 64 + mq * 4;
  const int swz = bg & 7;
  float acc[4][8];
  #pragma unroll
  for (int a = 0; a < 4; ++a)
    #pragma unroll
    for (int c = 0; c < 8; ++c) acc[a][c] = 0.f;
  for (int sc = blockIdx.y; sc < 65; sc += 16) {
    const int j0 = sc * 16;
    const int nj = min(16, 1025 - j0);
    __syncthreads();
    #pragma unroll
    for (int k = 0; k < 8; ++k) {
      const int e = k * 256 + tid;
      const int jl = e & 15, b = e >> 4;
      const int jg = j0 + jl;
      if (jg <= 1024) {
        const float v = (jg < 1024) ? K_V_C * x[b * 1024 + jg] : K_V_C;
        float u1, u2, u3;
        interp3(v, u1, u2, u3);
        U[b * 16 + (jl ^ ((b >> 3) & 7))] = make_float4(0.f, u1, u2, u3);
      }
    }
    __syncthreads();
    for (int jl = 0; jl < nj; ++jl) {
      const int jg = j0 + jl;
      const float4 wv = (jg < 1024) ? *(const float4*)(w + jg * 1024 + m0)
                                    : *(const float4*)(bias + m0);
      const float warr[4] = {wv.x, wv.y, wv.z, wv.w};
      float c1[4], c2[4], c3[4];
      #pragma unroll
      for (int mi = 0; mi < 4; ++mi) coeff3(kG * warr[mi], c1[mi], c2[mi], c3[mi]);
      const int base = bg * 128 + (jl ^ swz);
      #pragma unroll
      for (int bb = 0; bb < 8; ++bb) {
        const float4 u = U[base + bb * 16];
        #pragma unroll
        for (int mi = 0; mi < 4; ++mi)
          acc[mi][bb] = fmaf(c1[mi], u.y, fmaf(c2[mi], u.z, fmaf(c3[mi], u.w, acc[mi][bb])));
      }
    }
  }
  #pragma unroll
  for (int bb = 0; bb < 8; ++bb) {
    const int b = bg * 8 + bb;
    #pragma unroll
    for (int mi = 0; mi < 4; ++mi)
      atomicAdd(&out[b * 1024 + m0 + mi], acc[mi][bb] * scale);
  }
}

// ---------------------------------------------------------------------------
extern "C" void kernel_launch(void* const* d_in, const int* in_sizes, int n_in,
                              void* d_out, int out_size, void* d_ws, size_t ws_size,
                              hipStream_t stream) {
  const float* x = (const float*)d_in[0];   // (128, 1024)
  const float* w = (const float*)d_in[1];   // (1024, 1024)
  const float* b = (const float*)d_in[2];   // (1024,)
  float* out = (float*)d_out;               // (128, 1024) fp32

  unsigned int*   counter  = (unsigned int*)d_ws;
  float*          partials = (float*)((char*)d_ws + 128);        // 512 f32
  unsigned short* Ub = (unsigned short*)((char*)d_ws + 8192);    // 1,179,648 B
  const size_t need = 8192 + (size_t)128 * KP4 * 2;              // ~1.13 MB

  if (ws_size >= need) {
    hipMemsetAsync(counter, 0, 4, stream);
    mono_kernel<<<512, 512, 0, stream>>>(x, w, b, counter, partials, Ub, out);
  } else {                                 // fallback: tiny ws, atomic path
    unsigned int* wsmax = (unsigned int*)d_ws;
    hipMemsetAsync(wsmax, 0, 4, stream);
    maxabs_atomic_kernel<<<256, 256, 0, stream>>>(w, b, wsmax);
    hipMemsetAsync(out, 0, (size_t)out_size * sizeof(float), stream);
    dim3 grid(16, 16);
    memristor_atomic_kernel<<<grid, 256, 0, stream>>>(x, w, b, wsmax, out);
  }
}

// Round 14
// 28.163 us; speedup vs baseline: 4.1211x; 4.0970x over previous
//
#include <hip/hip_runtime.h>
#include <hip/hip_bf16.h>
#include <cstdint>

#define K_V_C   1.05f
#define G_DIFF  4.0e-4f   // G_MAX - G_MIN
#define KP4     4608      // k = 4*j + level (level 3 = zero pad), j padded to 1152

typedef __attribute__((ext_vector_type(8))) short short8;
typedef __attribute__((ext_vector_type(4))) float f32x4;

// I_REF rows 1..3 (row 0 is all zeros)
__device__ __constant__ float c_I1[9] = {-0.00015f,-0.00011f,-7e-05f,-3e-05f,0.f,3e-05f,7e-05f,0.00011f,0.00015f};
__device__ __constant__ float c_I2[9] = {-0.0005f,-0.00035f,-0.00022f,-9e-05f,0.f,9e-05f,0.00022f,0.00035f,0.0005f};
__device__ __constant__ float c_I3[9] = {-0.0009f,-0.0006f,-0.00037f,-0.00015f,0.f,0.00015f,0.00037f,0.0006f,0.0009f};

__device__ inline unsigned short f2bf(float f) {   // fp32 -> bf16 RNE
  unsigned int u = __float_as_uint(f);
  u += 0x7FFFu + ((u >> 16) & 1u);
  return (unsigned short)(u >> 16);
}

__device__ inline void interp3(float v, float& u1, float& u2, float& u3) {
  const float sf = v * 3.3333333333333335f + 4.0f;   // (v+1.2)/0.3
  float fs = floorf(sf);
  fs = fminf(fmaxf(fs, 0.f), 7.f);
  const int   s  = (int)fs;
  const float fr = fminf(fmaxf(sf - fs, 0.f), 1.f);
  u1 = fmaf(fr, c_I1[s+1] - c_I1[s], c_I1[s]);
  u2 = fmaf(fr, c_I2[s+1] - c_I2[s], c_I2[s]);
  u3 = fmaf(fr, c_I3[s+1] - c_I3[s], c_I3[s]);
}

// branch-free coeff3: clamped ramps, differences, sign OR'd in.
__device__ inline void coeff3f(float g, float& c1, float& c2, float& c3) {
  const float    ga = fabsf(g);
  const unsigned sb = __float_as_uint(g) & 0x80000000u;
  const float t1 = fminf(ga * 1e4f, 1.f);
  const float t2 = fminf(fmaxf((ga - 1e-4f) * 5e3f, 0.f), 1.f);
  const float t3 = fmaxf((ga - 3e-4f) * 5e3f, 0.f);
  c1 = __uint_as_float(__float_as_uint(t1 - t2) | sb);
  c2 = __uint_as_float(__float_as_uint(t2 - t3) | sb);
  c3 = __uint_as_float(__float_as_uint(t3) | sb);
}

__device__ inline void coeff3(float g, float& c1, float& c2, float& c3) {
  const float ga  = fabsf(g);
  const float sgn = (g > 0.f) ? 1.f : ((g < 0.f) ? -1.f : 0.f);
  const int   idx = (ga >= 3e-4f) ? 2 : ((ga >= 1e-4f) ? 1 : 0);
  const float g0   = (idx == 0) ? 0.f : ((idx == 1) ? 1e-4f : 3e-4f);
  const float invd = (idx == 0) ? 1e4f : 5e3f;
  const float t    = (ga - g0) * invd;
  const float clo = sgn * (1.f - t), chi = sgn * t;
  c1 = (idx == 0) ? chi : ((idx == 1) ? clo : 0.f);
  c2 = (idx == 1) ? chi : ((idx == 2) ? clo : 0.f);
  c3 = (idx == 2) ? chi : 0.f;
}

// ---------------------------------------------------------------------------
// Dispatch 1: blocks 0..1023  -> per-block max(|w|,|b|) partials (no atomics)
//             blocks 1024..1167 -> prep U bf16 [128][KP4], k = 4*j + level
// ---------------------------------------------------------------------------
__global__ __launch_bounds__(256) void prep1_kernel(
    const float* __restrict__ x, const float* __restrict__ w,
    const float* __restrict__ bias, float* __restrict__ partials,
    unsigned short* __restrict__ Ub) {
  const int t = threadIdx.x, bid = blockIdx.x;
  if (bid < 1024) {                       // ---- maxabs partial ----
    const int i = bid * 256 + t;          // one float4 of w per thread
    const float4 v = ((const float4*)w)[i];
    float m = fmaxf(fmaxf(fabsf(v.x), fabsf(v.y)), fmaxf(fabsf(v.z), fabsf(v.w)));
    if (i < 256) {
      const float4 bv = ((const float4*)bias)[i];
      m = fmaxf(m, fmaxf(fmaxf(fabsf(bv.x), fabsf(bv.y)),
                         fmaxf(fabsf(bv.z), fabsf(bv.w))));
    }
    #pragma unroll
    for (int o = 32; o > 0; o >>= 1) m = fmaxf(m, __shfl_down(m, o, 64));
    __shared__ float red[4];
    if ((t & 63) == 0) red[t >> 6] = m;
    __syncthreads();
    if (t == 0)
      partials[bid] = fmaxf(fmaxf(red[0], red[1]), fmaxf(red[2], red[3]));
  } else {                                // ---- prep U ----
    const int idx = (bid - 1024) * 256 + t;   // 36864 = 128 b x 288 j4-groups
    const int b = idx / 288, j4 = idx - b * 288;
    ushort4 o0 = make_ushort4(0,0,0,0), o1 = o0, o2 = o0, o3 = o0;
    if (j4 < 256) {
      const float4 xv = ((const float4*)x)[b * 256 + j4];
      float u1, u2, u3;
      interp3(K_V_C * xv.x, u1, u2, u3); o0 = make_ushort4(f2bf(u1), f2bf(u2), f2bf(u3), 0);
      interp3(K_V_C * xv.y, u1, u2, u3); o1 = make_ushort4(f2bf(u1), f2bf(u2), f2bf(u3), 0);
      interp3(K_V_C * xv.z, u1, u2, u3); o2 = make_ushort4(f2bf(u1), f2bf(u2), f2bf(u3), 0);
      interp3(K_V_C * xv.w, u1, u2, u3); o3 = make_ushort4(f2bf(u1), f2bf(u2), f2bf(u3), 0);
    } else if (j4 == 256) {               // j = 1024: ones/bias column
      float u1, u2, u3;
      interp3(K_V_C, u1, u2, u3);
      o0 = make_ushort4(f2bf(u1), f2bf(u2), f2bf(u3), 0);
    }
    ushort4* dst = (ushort4*)(Ub + (size_t)b * KP4 + j4 * 16);
    dst[0] = o0; dst[1] = o1; dst[2] = o2; dst[3] = o3;
  }
}

// ---------------------------------------------------------------------------
// Dispatch 2: GEMM y = scale * U . C^T, C-fragments built from an LDS-staged
//   w-panel. 512 blocks (one 16x16 tile) x 8 waves (split-K x8, 144 j each).
//   LDS panel [1024 j][16 m] f32 (64 KB). ALL 18 A-fragments preloaded into
//   registers (72 VGPR) so no load latency in the loop; B-fragments packed
//   with HW v_cvt_pk_bf16_f32 (4 instr/step vs header bf16 conversion).
// ---------------------------------------------------------------------------
__global__ __launch_bounds__(512, 4) void fusedgemm_kernel(
    const float* __restrict__ w, const float* __restrict__ bias,
    const float* __restrict__ partials, const unsigned short* __restrict__ Ub,
    float* __restrict__ out) {
  __shared__ __align__(16) float lds[16384];   // 64 KB exactly
  const int t = threadIdx.x;
  const int wv = t >> 6, lane = t & 63, la = lane & 15, kg = lane >> 4;
  const int b0 = (blockIdx.x >> 6) * 16;
  const int n0 = (blockIdx.x & 63) * 16;
  const int m  = n0 + la;

  // ---- preload all 18 A-fragments (issued before staging; deep pipeline) ----
  const unsigned short* Ap = Ub + (size_t)(b0 + la) * KP4 + wv * 576 + kg * 8;
  short8 areg[18];
  #pragma unroll
  for (int ks = 0; ks < 18; ++ks) areg[ks] = *(const short8*)(Ap + ks * 32);

  // ---- stage w-panel: lds[j][mm] = w[j][n0+mm]  (contiguous b128 writes) ----
  #pragma unroll
  for (int i = 0; i < 8; ++i) {
    const int idx = i * 512 + t;               // 4096 float4 of the panel
    const int row = idx >> 2, c4 = idx & 3;    // row = j
    const float4 v = *(const float4*)(w + (size_t)row * 1024 + n0 + c4 * 4);
    *(float4*)&lds[row * 16 + c4 * 4] = v;
  }

  // ---- maxw from all 1024 partials ----
  float mx = 0.f;
  #pragma unroll
  for (int i = 0; i < 4; ++i) {
    const float4 p = ((const float4*)partials)[lane + i * 64];
    mx = fmaxf(mx, fmaxf(fmaxf(p.x, p.y), fmaxf(p.z, p.w)));
  }
  #pragma unroll
  for (int o = 1; o < 64; o <<= 1) mx = fmaxf(mx, __shfl_xor(mx, o, 64));
  const float maxw = mx;
  const float kG   = G_DIFF / maxw;
  const float bv   = bias[m];
  __syncthreads();

  // ---- 18-step branch-free MFMA loop (wave = k-slice of 576 = 144 j) ----
  const int jb = wv * 144 + kg * 2;
  f32x4 acc = {0.f, 0.f, 0.f, 0.f};
  #pragma unroll
  for (int ks = 0; ks < 18; ++ks) {
    const int j0 = jb + ks * 8;                // this lane's two j's: j0, j0+1
    const float ra = lds[(j0 & 1023) * 16 + la];
    const float rb = lds[((j0 + 1) & 1023) * 16 + la];
    const float wa = (j0 < 1024) ? ra : ((j0 == 1024) ? bv : 0.f);
    const float wb = (j0 + 1 < 1024) ? rb : ((j0 + 1 == 1024) ? bv : 0.f);
    float a1, a2, a3, b1, b2, b3;
    coeff3f(kG * wa, a1, a2, a3);
    coeff3f(kG * wb, b1, b2, b3);
    unsigned int p0, p1, p2, p3;
    asm("v_cvt_pk_bf16_f32 %0, %1, %2" : "=v"(p0) : "v"(a1), "v"(a2));
    asm("v_cvt_pk_bf16_f32 %0, %1, %2" : "=v"(p1) : "v"(a3), "v"(0.f));
    asm("v_cvt_pk_bf16_f32 %0, %1, %2" : "=v"(p2) : "v"(b1), "v"(b2));
    asm("v_cvt_pk_bf16_f32 %0, %1, %2" : "=v"(p3) : "v"(b3), "v"(0.f));
    union { unsigned int u[4]; short8 s; } bf;
    bf.u[0] = p0; bf.u[1] = p1; bf.u[2] = p2; bf.u[3] = p3;
    acc = __builtin_amdgcn_mfma_f32_16x16x32_bf16(areg[ks], bf.s, acc, 0, 0, 0);
  }

  // ---- cross-wave K-reduce (P aliases the w-panel) + fused scale ----
  __syncthreads();                             // all waves done reading panel
  *(float4*)&lds[wv * 256 + lane * 4] = make_float4(acc[0], acc[1], acc[2], acc[3]);
  __syncthreads();
  if (t < 256) {
    float s = 0.f;
    #pragma unroll
    for (int ww = 0; ww < 8; ++ww) s += lds[ww * 256 + t];
    const int l2 = t >> 2, ai = t & 3;         // D: col = lane&15, row = kg*4+r
    const int row = b0 + ((l2 >> 4) << 2) + ai;
    const int col = n0 + (l2 & 15);
    out[(size_t)row * 1024 + col] = s * (maxw * (1.0f / (K_V_C * G_DIFF)));
  }
}

// ---------------------------------------------------------------------------
// Fallback (tiny ws): atomic-based path, needs only 4 bytes of ws.
// ---------------------------------------------------------------------------
__global__ __launch_bounds__(256) void maxabs_atomic_kernel(
    const float* __restrict__ w, const float* __restrict__ b,
    unsigned int* __restrict__ wsmax) {
  const int NW4 = 262144, NB4 = 256;
  float m = 0.f;
  for (int i = blockIdx.x * blockDim.x + threadIdx.x; i < NW4 + NB4;
       i += gridDim.x * blockDim.x) {
    float4 v = (i < NW4) ? ((const float4*)w)[i] : ((const float4*)b)[i - NW4];
    m = fmaxf(m, fmaxf(fmaxf(fabsf(v.x), fabsf(v.y)),
                       fmaxf(fabsf(v.z), fabsf(v.w))));
  }
  #pragma unroll
  for (int o = 32; o > 0; o >>= 1) m = fmaxf(m, __shfl_down(m, o, 64));
  __shared__ float red[4];
  if ((threadIdx.x & 63) == 0) red[threadIdx.x >> 6] = m;
  __syncthreads();
  if (threadIdx.x == 0)
    atomicMax(wsmax, __float_as_uint(fmaxf(fmaxf(red[0], red[1]),
                                           fmaxf(red[2], red[3]))));
}

__global__ __launch_bounds__(256) void memristor_atomic_kernel(
    const float* __restrict__ x, const float* __restrict__ w,
    const float* __restrict__ bias, const unsigned int* __restrict__ wsmax,
    float* __restrict__ out) {
  __shared__ float4 U[2048];
  const int tid = threadIdx.x;
  const float maxw  = __uint_as_float(*wsmax);
  const float kG    = G_DIFF / maxw;
  const float scale = maxw * (1.0f / (K_V_C * G_DIFF));
  const int mq = tid & 15, bg = tid >> 4;
  const int m0 = blockIdx.x * 64 + mq * 4;
  const int swz = bg & 7;
  float acc[4][8];
  #pragma unroll
  for (int a = 0; a < 4; ++a)
    #pragma unroll
    for (int c = 0; c < 8; ++c) acc[a][c] = 0.f;
  for (int sc = blockIdx.y; sc < 65; sc += 16) {
    const int j0 = sc * 16;
    const int nj = min(16, 1025 - j0);
    __syncthreads();
    #pragma unroll
    for (int k = 0; k < 8; ++k) {
      const int e = k * 256 + tid;
      const int jl = e & 15, b = e >> 4;
      const int jg = j0 + jl;
      if (jg <= 1024) {
        const float v = (jg < 1024) ? K_V_C * x[b * 1024 + jg] : K_V_C;
        float u1, u2, u3;
        interp3(v, u1, u2, u3);
        U[b * 16 + (jl ^ ((b >> 3) & 7))] = make_float4(0.f, u1, u2, u3);
      }
    }
    __syncthreads();
    for (int jl = 0; jl < nj; ++jl) {
      const int jg = j0 + jl;
      const float4 wv = (jg < 1024) ? *(const float4*)(w + jg * 1024 + m0)
                                    : *(const float4*)(bias + m0);
      const float warr[4] = {wv.x, wv.y, wv.z, wv.w};
      float c1[4], c2[4], c3[4];
      #pragma unroll
      for (int mi = 0; mi < 4; ++mi) coeff3(kG * warr[mi], c1[mi], c2[mi], c3[mi]);
      const int base = bg * 128 + (jl ^ swz);
      #pragma unroll
      for (int bb = 0; bb < 8; ++bb) {
        const float4 u = U[base + bb * 16];
        #pragma unroll
        for (int mi = 0; mi < 4; ++mi)
          acc[mi][bb] = fmaf(c1[mi], u.y, fmaf(c2[mi], u.z, fmaf(c3[mi], u.w, acc[mi][bb])));
      }
    }
  }
  #pragma unroll
  for (int bb = 0; bb < 8; ++bb) {
    const int b = bg * 8 + bb;
    #pragma unroll
    for (int mi = 0; mi < 4; ++mi)
      atomicAdd(&out[b * 1024 + m0 + mi], acc[mi][bb] * scale);
  }
}

// ---------------------------------------------------------------------------
extern "C" void kernel_launch(void* const* d_in, const int* in_sizes, int n_in,
                              void* d_out, int out_size, void* d_ws, size_t ws_size,
                              hipStream_t stream) {
  const float* x = (const float*)d_in[0];   // (128, 1024)
  const float* w = (const float*)d_in[1];   // (1024, 1024)
  const float* b = (const float*)d_in[2];   // (1024,)
  float* out = (float*)d_out;               // (128, 1024) fp32

  float*          partials = (float*)((char*)d_ws + 128);        // 1024 f32
  unsigned short* Ub = (unsigned short*)((char*)d_ws + 8192);    // 1,179,648 B
  const size_t need = 8192 + (size_t)128 * KP4 * 2;              // ~1.13 MB

  if (ws_size >= need) {
    prep1_kernel<<<1168, 256, 0, stream>>>(x, w, b, partials, Ub);
    fusedgemm_kernel<<<512, 512, 0, stream>>>(w, b, partials, Ub, out);
  } else {                                 // fallback: tiny ws, atomic path
    unsigned int* wsmax = (unsigned int*)d_ws;
    hipMemsetAsync(wsmax, 0, 4, stream);
    maxabs_atomic_kernel<<<256, 256, 0, stream>>>(w, b, wsmax);
    hipMemsetAsync(out, 0, (size_t)out_size * sizeof(float), stream);
    dim3 grid(16, 16);
    memristor_atomic_kernel<<<grid, 256, 0, stream>>>(x, w, b, wsmax, out);
  }
}

// Round 15
// 21.882 us; speedup vs baseline: 5.3040x; 1.2870x over previous
//
#include <hip/hip_runtime.h>
#include <hip/hip_bf16.h>
#include <cstdint>

#define K_V_C   1.05f
#define G_DIFF  4.0e-4f   // G_MAX - G_MIN
#define KP4     4608      // k = 4*j + level (level 3 = zero pad), j padded to 1152

typedef __attribute__((ext_vector_type(8))) short short8;
typedef __attribute__((ext_vector_type(4))) float f32x4;

// I_REF rows 1..3 (row 0 is all zeros)
__device__ __constant__ float c_I1[9] = {-0.00015f,-0.00011f,-7e-05f,-3e-05f,0.f,3e-05f,7e-05f,0.00011f,0.00015f};
__device__ __constant__ float c_I2[9] = {-0.0005f,-0.00035f,-0.00022f,-9e-05f,0.f,9e-05f,0.00022f,0.00035f,0.0005f};
__device__ __constant__ float c_I3[9] = {-0.0009f,-0.0006f,-0.00037f,-0.00015f,0.f,0.00015f,0.00037f,0.0006f,0.0009f};

__device__ inline unsigned short f2bf(float f) {   // fp32 -> bf16 RNE
  unsigned int u = __float_as_uint(f);
  u += 0x7FFFu + ((u >> 16) & 1u);
  return (unsigned short)(u >> 16);
}

__device__ inline void interp3(float v, float& u1, float& u2, float& u3) {
  const float sf = v * 3.3333333333333335f + 4.0f;   // (v+1.2)/0.3
  float fs = floorf(sf);
  fs = fminf(fmaxf(fs, 0.f), 7.f);
  const int   s  = (int)fs;
  const float fr = fminf(fmaxf(sf - fs, 0.f), 1.f);
  u1 = fmaf(fr, c_I1[s+1] - c_I1[s], c_I1[s]);
  u2 = fmaf(fr, c_I2[s+1] - c_I2[s], c_I2[s]);
  u3 = fmaf(fr, c_I3[s+1] - c_I3[s], c_I3[s]);
}

// branch-free coeff3: clamped ramps, differences, sign OR'd in.
__device__ inline void coeff3f(float g, float& c1, float& c2, float& c3) {
  const float    ga = fabsf(g);
  const unsigned sb = __float_as_uint(g) & 0x80000000u;
  const float t1 = fminf(ga * 1e4f, 1.f);
  const float t2 = fminf(fmaxf((ga - 1e-4f) * 5e3f, 0.f), 1.f);
  const float t3 = fmaxf((ga - 3e-4f) * 5e3f, 0.f);
  c1 = __uint_as_float(__float_as_uint(t1 - t2) | sb);
  c2 = __uint_as_float(__float_as_uint(t2 - t3) | sb);
  c3 = __uint_as_float(__float_as_uint(t3) | sb);
}

__device__ inline void coeff3(float g, float& c1, float& c2, float& c3) {
  const float ga  = fabsf(g);
  const float sgn = (g > 0.f) ? 1.f : ((g < 0.f) ? -1.f : 0.f);
  const int   idx = (ga >= 3e-4f) ? 2 : ((ga >= 1e-4f) ? 1 : 0);
  const float g0   = (idx == 0) ? 0.f : ((idx == 1) ? 1e-4f : 3e-4f);
  const float invd = (idx == 0) ? 1e4f : 5e3f;
  const float t    = (ga - g0) * invd;
  const float clo = sgn * (1.f - t), chi = sgn * t;
  c1 = (idx == 0) ? chi : ((idx == 1) ? clo : 0.f);
  c2 = (idx == 1) ? chi : ((idx == 2) ? clo : 0.f);
  c3 = (idx == 2) ? chi : 0.f;
}

// ---------------------------------------------------------------------------
// Dispatch 1: blocks 0..1023  -> per-block max(|w|,|b|) partials (no atomics)
//             blocks 1024..1167 -> prep U bf16 [128][KP4], k = 4*j + level
// ---------------------------------------------------------------------------
__global__ __launch_bounds__(256) void prep1_kernel(
    const float* __restrict__ x, const float* __restrict__ w,
    const float* __restrict__ bias, float* __restrict__ partials,
    unsigned short* __restrict__ Ub) {
  const int t = threadIdx.x, bid = blockIdx.x;
  if (bid < 1024) {                       // ---- maxabs partial ----
    const int i = bid * 256 + t;          // one float4 of w per thread
    const float4 v = ((const float4*)w)[i];
    float m = fmaxf(fmaxf(fabsf(v.x), fabsf(v.y)), fmaxf(fabsf(v.z), fabsf(v.w)));
    if (i < 256) {
      const float4 bv = ((const float4*)bias)[i];
      m = fmaxf(m, fmaxf(fmaxf(fabsf(bv.x), fabsf(bv.y)),
                         fmaxf(fabsf(bv.z), fabsf(bv.w))));
    }
    #pragma unroll
    for (int o = 32; o > 0; o >>= 1) m = fmaxf(m, __shfl_down(m, o, 64));
    __shared__ float red[4];
    if ((t & 63) == 0) red[t >> 6] = m;
    __syncthreads();
    if (t == 0)
      partials[bid] = fmaxf(fmaxf(red[0], red[1]), fmaxf(red[2], red[3]));
  } else {                                // ---- prep U ----
    const int idx = (bid - 1024) * 256 + t;   // 36864 = 128 b x 288 j4-groups
    const int b = idx / 288, j4 = idx - b * 288;
    ushort4 o0 = make_ushort4(0,0,0,0), o1 = o0, o2 = o0, o3 = o0;
    if (j4 < 256) {
      const float4 xv = ((const float4*)x)[b * 256 + j4];
      float u1, u2, u3;
      interp3(K_V_C * xv.x, u1, u2, u3); o0 = make_ushort4(f2bf(u1), f2bf(u2), f2bf(u3), 0);
      interp3(K_V_C * xv.y, u1, u2, u3); o1 = make_ushort4(f2bf(u1), f2bf(u2), f2bf(u3), 0);
      interp3(K_V_C * xv.z, u1, u2, u3); o2 = make_ushort4(f2bf(u1), f2bf(u2), f2bf(u3), 0);
      interp3(K_V_C * xv.w, u1, u2, u3); o3 = make_ushort4(f2bf(u1), f2bf(u2), f2bf(u3), 0);
    } else if (j4 == 256) {               // j = 1024: ones/bias column
      float u1, u2, u3;
      interp3(K_V_C, u1, u2, u3);
      o0 = make_ushort4(f2bf(u1), f2bf(u2), f2bf(u3), 0);
    }
    ushort4* dst = (ushort4*)(Ub + (size_t)b * KP4 + j4 * 16);
    dst[0] = o0; dst[1] = o1; dst[2] = o2; dst[3] = o3;
  }
}

// ---------------------------------------------------------------------------
// Dispatch 2: GEMM y = scale * U . C^T, C-fragments built from an LDS-staged
//   bf16 w-panel [1152 j][16 m] (36 KB; row 1024 = bias, rows 1025+ = 0 so
//   the inner loop has NO boundary selects). 512 blocks x 8 waves, split-K x8
//   (144 j per wave), 18 MFMA steps. 36 KB LDS -> 4 blocks/CU -> 32 waves/CU
//   (2x the latency hiding of the r11 f32-panel version). r11 loop body kept
//   verbatim otherwise (r14's reg-preload + asm cvt_pk both regressed).
// ---------------------------------------------------------------------------
__global__ __launch_bounds__(512, 8) void fusedgemm_kernel(
    const float* __restrict__ w, const float* __restrict__ bias,
    const float* __restrict__ partials, const unsigned short* __restrict__ Ub,
    float* __restrict__ out) {
  __shared__ __align__(16) unsigned short panel[18432];   // 36 KB: [1152][16]
  const int t = threadIdx.x;
  const int wv = t >> 6, lane = t & 63, la = lane & 15, kg = lane >> 4;
  const int b0 = (blockIdx.x >> 6) * 16;
  const int n0 = (blockIdx.x & 63) * 16;

  // ---- stage bf16 w-panel: panel[j][mm] = bf16(w[j][n0+mm]) ----
  #pragma unroll
  for (int i = 0; i < 8; ++i) {
    const int idx = i * 512 + t;               // 4096 float4 of the w panel
    const int row = idx >> 2, c4 = idx & 3;    // row = j
    const float4 v = *(const float4*)(w + (size_t)row * 1024 + n0 + c4 * 4);
    panel[row * 16 + c4 * 4 + 0] = f2bf(v.x);
    panel[row * 16 + c4 * 4 + 1] = f2bf(v.y);
    panel[row * 16 + c4 * 4 + 2] = f2bf(v.z);
    panel[row * 16 + c4 * 4 + 3] = f2bf(v.w);
  }
  if (t < 16) panel[1024 * 16 + t] = f2bf(bias[n0 + t]);   // row 1024 = bias
  for (int i = 1025 * 16 + t; i < 1152 * 16; i += 512) panel[i] = 0;

  // ---- maxw from all 1024 partials ----
  float mx = 0.f;
  #pragma unroll
  for (int i = 0; i < 4; ++i) {
    const float4 p = ((const float4*)partials)[lane + i * 64];
    mx = fmaxf(mx, fmaxf(fmaxf(p.x, p.y), fmaxf(p.z, p.w)));
  }
  #pragma unroll
  for (int o = 1; o < 64; o <<= 1) mx = fmaxf(mx, __shfl_xor(mx, o, 64));
  const float maxw = mx;
  const float kG   = G_DIFF / maxw;
  __syncthreads();

  // ---- 18-step branch-free MFMA loop (wave = k-slice of 576 = 144 j) ----
  const unsigned short* Ap = Ub + (size_t)(b0 + la) * KP4 + wv * 576 + kg * 8;
  const int jb = wv * 144 + kg * 2;
  f32x4 acc = {0.f, 0.f, 0.f, 0.f};
  #pragma unroll 6
  for (int ks = 0; ks < 18; ++ks) {
    const short8 a = *(const short8*)(Ap + ks * 32);
    const int j0 = jb + ks * 8;                // this lane's two j's: j0, j0+1
    const float wa = __uint_as_float((unsigned)panel[j0 * 16 + la] << 16);
    const float wb = __uint_as_float((unsigned)panel[(j0 + 1) * 16 + la] << 16);
    float a1, a2, a3, b1, b2, b3;
    coeff3f(kG * wa, a1, a2, a3);
    coeff3f(kG * wb, b1, b2, b3);
    union { __hip_bfloat162 h[4]; short8 s; } bf;
    bf.h[0] = __float22bfloat162_rn(make_float2(a1, a2));
    bf.h[1] = __float22bfloat162_rn(make_float2(a3, 0.f));
    bf.h[2] = __float22bfloat162_rn(make_float2(b1, b2));
    bf.h[3] = __float22bfloat162_rn(make_float2(b3, 0.f));
    acc = __builtin_amdgcn_mfma_f32_16x16x32_bf16(a, bf.s, acc, 0, 0, 0);
  }

  // ---- cross-wave K-reduce (P aliases the panel) + fused scale ----
  float* P = (float*)panel;                    // 8 KB < 36 KB, after barrier
  __syncthreads();                             // all waves done reading panel
  *(float4*)&P[wv * 256 + lane * 4] = make_float4(acc[0], acc[1], acc[2], acc[3]);
  __syncthreads();
  if (t < 256) {
    float s = 0.f;
    #pragma unroll
    for (int ww = 0; ww < 8; ++ww) s += P[ww * 256 + t];
    const int l2 = t >> 2, ai = t & 3;         // D: col = lane&15, row = kg*4+r
    const int row = b0 + ((l2 >> 4) << 2) + ai;
    const int col = n0 + (l2 & 15);
    out[(size_t)row * 1024 + col] = s * (maxw * (1.0f / (K_V_C * G_DIFF)));
  }
}

// ---------------------------------------------------------------------------
// Fallback (tiny ws): atomic-based path, needs only 4 bytes of ws.
// ---------------------------------------------------------------------------
__global__ __launch_bounds__(256) void maxabs_atomic_kernel(
    const float* __restrict__ w, const float* __restrict__ b,
    unsigned int* __restrict__ wsmax) {
  const int NW4 = 262144, NB4 = 256;
  float m = 0.f;
  for (int i = blockIdx.x * blockDim.x + threadIdx.x; i < NW4 + NB4;
       i += gridDim.x * blockDim.x) {
    float4 v = (i < NW4) ? ((const float4*)w)[i] : ((const float4*)b)[i - NW4];
    m = fmaxf(m, fmaxf(fmaxf(fabsf(v.x), fabsf(v.y)),
                       fmaxf(fabsf(v.z), fabsf(v.w))));
  }
  #pragma unroll
  for (int o = 32; o > 0; o >>= 1) m = fmaxf(m, __shfl_down(m, o, 64));
  __shared__ float red[4];
  if ((threadIdx.x & 63) == 0) red[threadIdx.x >> 6] = m;
  __syncthreads();
  if (threadIdx.x == 0)
    atomicMax(wsmax, __float_as_uint(fmaxf(fmaxf(red[0], red[1]),
                                           fmaxf(red[2], red[3]))));
}

__global__ __launch_bounds__(256) void memristor_atomic_kernel(
    const float* __restrict__ x, const float* __restrict__ w,
    const float* __restrict__ bias, const unsigned int* __restrict__ wsmax,
    float* __restrict__ out) {
  __shared__ float4 U[2048];
  const int tid = threadIdx.x;
  const float maxw  = __uint_as_float(*wsmax);
  const float kG    = G_DIFF / maxw;
  const float scale = maxw * (1.0f / (K_V_C * G_DIFF));
  const int mq = tid & 15, bg = tid >> 4;
  const int m0 = blockIdx.x * 64 + mq * 4;
  const int swz = bg & 7;
  float acc[4][8];
  #pragma unroll
  for (int a = 0; a < 4; ++a)
    #pragma unroll
    for (int c = 0; c < 8; ++c) acc[a][c] = 0.f;
  for (int sc = blockIdx.y; sc < 65; sc += 16) {
    const int j0 = sc * 16;
    const int nj = min(16, 1025 - j0);
    __syncthreads();
    #pragma unroll
    for (int k = 0; k < 8; ++k) {
      const int e = k * 256 + tid;
      const int jl = e & 15, b = e >> 4;
      const int jg = j0 + jl;
      if (jg <= 1024) {
        const float v = (jg < 1024) ? K_V_C * x[b * 1024 + jg] : K_V_C;
        float u1, u2, u3;
        interp3(v, u1, u2, u3);
        U[b * 16 + (jl ^ ((b >> 3) & 7))] = make_float4(0.f, u1, u2, u3);
      }
    }
    __syncthreads();
    for (int jl = 0; jl < nj; ++jl) {
      const int jg = j0 + jl;
      const float4 wv = (jg < 1024) ? *(const float4*)(w + jg * 1024 + m0)
                                    : *(const float4*)(bias + m0);
      const float warr[4] = {wv.x, wv.y, wv.z, wv.w};
      float c1[4], c2[4], c3[4];
      #pragma unroll
      for (int mi = 0; mi < 4; ++mi) coeff3(kG * warr[mi], c1[mi], c2[mi], c3[mi]);
      const int base = bg * 128 + (jl ^ swz);
      #pragma unroll
      for (int bb = 0; bb < 8; ++bb) {
        const float4 u = U[base + bb * 16];
        #pragma unroll
        for (int mi = 0; mi < 4; ++mi)
          acc[mi][bb] = fmaf(c1[mi], u.y, fmaf(c2[mi], u.z, fmaf(c3[mi], u.w, acc[mi][bb])));
      }
    }
  }
  #pragma unroll
  for (int bb = 0; bb < 8; ++bb) {
    const int b = bg * 8 + bb;
    #pragma unroll
    for (int mi = 0; mi < 4; ++mi)
      atomicAdd(&out[b * 1024 + m0 + mi], acc[mi][bb] * scale);
  }
}

// ---------------------------------------------------------------------------
extern "C" void kernel_launch(void* const* d_in, const int* in_sizes, int n_in,
                              void* d_out, int out_size, void* d_ws, size_t ws_size,
                              hipStream_t stream) {
  const float* x = (const float*)d_in[0];   // (128, 1024)
  const float* w = (const float*)d_in[1];   // (1024, 1024)
  const float* b = (const float*)d_in[2];   // (1024,)
  float* out = (float*)d_out;               // (128, 1024) fp32

  float*          partials = (float*)((char*)d_ws + 128);        // 1024 f32
  unsigned short* Ub = (unsigned short*)((char*)d_ws + 8192);    // 1,179,648 B
  const size_t need = 8192 + (size_t)128 * KP4 * 2;              // ~1.13 MB

  if (ws_size >= need) {
    prep1_kernel<<<1168, 256, 0, stream>>>(x, w, b, partials, Ub);
    fusedgemm_kernel<<<512, 512, 0, stream>>>(w, b, partials, Ub, out);
  } else {                                 // fallback: tiny ws, atomic path
    unsigned int* wsmax = (unsigned int*)d_ws;
    hipMemsetAsync(wsmax, 0, 4, stream);
    maxabs_atomic_kernel<<<256, 256, 0, stream>>>(w, b, wsmax);
    hipMemsetAsync(out, 0, (size_t)out_size * sizeof(float), stream);
    dim3 grid(16, 16);
    memristor_atomic_kernel<<<grid, 256, 0, stream>>>(x, w, b, wsmax, out);
  }
}

// Round 16
// 18.465 us; speedup vs baseline: 6.2855x; 1.1850x over previous
//
#include <hip/hip_runtime.h>
#include <hip/hip_bf16.h>
#include <cstdint>

#define K_V_C   1.05f
#define G_DIFF  4.0e-4f   // G_MAX - G_MIN
#define KP4     4608      // k = 4*j + level (level 3 = zero pad), j padded to 1152

typedef __attribute__((ext_vector_type(8))) short short8;
typedef __attribute__((ext_vector_type(4))) float f32x4;

// I_REF rows 1..3 (row 0 is all zeros)
__device__ __constant__ float c_I1[9] = {-0.00015f,-0.00011f,-7e-05f,-3e-05f,0.f,3e-05f,7e-05f,0.00011f,0.00015f};
__device__ __constant__ float c_I2[9] = {-0.0005f,-0.00035f,-0.00022f,-9e-05f,0.f,9e-05f,0.00022f,0.00035f,0.0005f};
__device__ __constant__ float c_I3[9] = {-0.0009f,-0.0006f,-0.00037f,-0.00015f,0.f,0.00015f,0.00037f,0.0006f,0.0009f};

__device__ inline unsigned short f2bf(float f) {   // fp32 -> bf16 RNE
  unsigned int u = __float_as_uint(f);
  u += 0x7FFFu + ((u >> 16) & 1u);
  return (unsigned short)(u >> 16);
}

__device__ inline float bf2f(unsigned short h) {
  return __uint_as_float((unsigned int)h << 16);
}

__device__ inline void interp3(float v, float& u1, float& u2, float& u3) {
  const float sf = v * 3.3333333333333335f + 4.0f;   // (v+1.2)/0.3
  float fs = floorf(sf);
  fs = fminf(fmaxf(fs, 0.f), 7.f);
  const int   s  = (int)fs;
  const float fr = fminf(fmaxf(sf - fs, 0.f), 1.f);
  u1 = fmaf(fr, c_I1[s+1] - c_I1[s], c_I1[s]);
  u2 = fmaf(fr, c_I2[s+1] - c_I2[s], c_I2[s]);
  u3 = fmaf(fr, c_I3[s+1] - c_I3[s], c_I3[s]);
}

// branch-free coeff3: clamped ramps, differences, sign OR'd in.
__device__ inline void coeff3f(float g, float& c1, float& c2, float& c3) {
  const float    ga = fabsf(g);
  const unsigned sb = __float_as_uint(g) & 0x80000000u;
  const float t1 = fminf(ga * 1e4f, 1.f);
  const float t2 = fminf(fmaxf((ga - 1e-4f) * 5e3f, 0.f), 1.f);
  const float t3 = fmaxf((ga - 3e-4f) * 5e3f, 0.f);
  c1 = __uint_as_float(__float_as_uint(t1 - t2) | sb);
  c2 = __uint_as_float(__float_as_uint(t2 - t3) | sb);
  c3 = __uint_as_float(__float_as_uint(t3) | sb);
}

__device__ inline void coeff3(float g, float& c1, float& c2, float& c3) {
  const float ga  = fabsf(g);
  const float sgn = (g > 0.f) ? 1.f : ((g < 0.f) ? -1.f : 0.f);
  const int   idx = (ga >= 3e-4f) ? 2 : ((ga >= 1e-4f) ? 1 : 0);
  const float g0   = (idx == 0) ? 0.f : ((idx == 1) ? 1e-4f : 3e-4f);
  const float invd = (idx == 0) ? 1e4f : 5e3f;
  const float t    = (ga - g0) * invd;
  const float clo = sgn * (1.f - t), chi = sgn * t;
  c1 = (idx == 0) ? chi : ((idx == 1) ? clo : 0.f);
  c2 = (idx == 1) ? chi : ((idx == 2) ? clo : 0.f);
  c3 = (idx == 2) ? chi : 0.f;
}

// ---------------------------------------------------------------------------
// Dispatch 1: blocks 0..1023  -> per-block max(|w|,|b|) partials (no atomics)
//             blocks 1024..1167 -> prep U bf16 [128][KP4], k = 4*j + level
// ---------------------------------------------------------------------------
__global__ __launch_bounds__(256) void prep1_kernel(
    const float* __restrict__ x, const float* __restrict__ w,
    const float* __restrict__ bias, float* __restrict__ partials,
    unsigned short* __restrict__ Ub) {
  const int t = threadIdx.x, bid = blockIdx.x;
  if (bid < 1024) {                       // ---- maxabs partial ----
    const int i = bid * 256 + t;          // one float4 of w per thread
    const float4 v = ((const float4*)w)[i];
    float m = fmaxf(fmaxf(fabsf(v.x), fabsf(v.y)), fmaxf(fabsf(v.z), fabsf(v.w)));
    if (i < 256) {
      const float4 bv = ((const float4*)bias)[i];
      m = fmaxf(m, fmaxf(fmaxf(fabsf(bv.x), fabsf(bv.y)),
                         fmaxf(fabsf(bv.z), fabsf(bv.w))));
    }
    #pragma unroll
    for (int o = 32; o > 0; o >>= 1) m = fmaxf(m, __shfl_down(m, o, 64));
    __shared__ float red[4];
    if ((t & 63) == 0) red[t >> 6] = m;
    __syncthreads();
    if (t == 0)
      partials[bid] = fmaxf(fmaxf(red[0], red[1]), fmaxf(red[2], red[3]));
  } else {                                // ---- prep U ----
    const int idx = (bid - 1024) * 256 + t;   // 36864 = 128 b x 288 j4-groups
    const int b = idx / 288, j4 = idx - b * 288;
    ushort4 o0 = make_ushort4(0,0,0,0), o1 = o0, o2 = o0, o3 = o0;
    if (j4 < 256) {
      const float4 xv = ((const float4*)x)[b * 256 + j4];
      float u1, u2, u3;
      interp3(K_V_C * xv.x, u1, u2, u3); o0 = make_ushort4(f2bf(u1), f2bf(u2), f2bf(u3), 0);
      interp3(K_V_C * xv.y, u1, u2, u3); o1 = make_ushort4(f2bf(u1), f2bf(u2), f2bf(u3), 0);
      interp3(K_V_C * xv.z, u1, u2, u3); o2 = make_ushort4(f2bf(u1), f2bf(u2), f2bf(u3), 0);
      interp3(K_V_C * xv.w, u1, u2, u3); o3 = make_ushort4(f2bf(u1), f2bf(u2), f2bf(u3), 0);
    } else if (j4 == 256) {               // j = 1024: ones/bias column
      float u1, u2, u3;
      interp3(K_V_C, u1, u2, u3);
      o0 = make_ushort4(f2bf(u1), f2bf(u2), f2bf(u3), 0);
    }
    ushort4* dst = (ushort4*)(Ub + (size_t)b * KP4 + j4 * 16);
    dst[0] = o0; dst[1] = o1; dst[2] = o2; dst[3] = o3;
  }
}

// ---------------------------------------------------------------------------
// Dispatch 2: wide-N GEMM. 256 blocks (16 b x 32 m tile each) x 16 waves
//   (1024 thr), split-K x16 (288 k = 9 MFMA steps per wave). Per step ONE
//   A-fragment load feeds TWO MFMAs (cols n0+la and n0+16+la) -> A-fragment
//   L2 traffic and serial chain length halved vs the 16-m version.
//   bf16 panel [1152 j][32 m] (72 KB; row 1024 = bias, 1025+ = 0, branch-free
//   inner loop). P[16][512] f32 (32 KB) aliases the panel for the K-reduce.
// ---------------------------------------------------------------------------
__global__ __launch_bounds__(1024, 4) void fusedgemm_kernel(
    const float* __restrict__ w, const float* __restrict__ bias,
    const float* __restrict__ partials, const unsigned short* __restrict__ Ub,
    float* __restrict__ out) {
  __shared__ __align__(16) unsigned short panel[36864];   // 72 KB: [1152][32]
  const int t = threadIdx.x;
  const int wv = t >> 6, lane = t & 63, la = lane & 15, kg = lane >> 4;
  const int b0 = (blockIdx.x >> 5) * 16;
  const int n0 = (blockIdx.x & 31) * 32;

  // ---- stage bf16 w-panel: panel[j][mm] = bf16(w[j][n0+mm]) ----
  #pragma unroll
  for (int i = 0; i < 8; ++i) {
    const int idx = i * 1024 + t;              // 8192 float4 of the w panel
    const int row = idx >> 3, c4 = idx & 7;    // row = j, 8 f4 per row
    const float4 v = *(const float4*)(w + (size_t)row * 1024 + n0 + c4 * 4);
    *(ushort4*)&panel[row * 32 + c4 * 4] =
        make_ushort4(f2bf(v.x), f2bf(v.y), f2bf(v.z), f2bf(v.w));
  }
  if (t < 32) panel[1024 * 32 + t] = f2bf(bias[n0 + t]);   // row 1024 = bias
  for (int i = 1025 * 32 + t; i < 1152 * 32; i += 1024) panel[i] = 0;

  // ---- maxw from all 1024 partials ----
  float mx = 0.f;
  #pragma unroll
  for (int i = 0; i < 4; ++i) {
    const float4 p = ((const float4*)partials)[lane + i * 64];
    mx = fmaxf(mx, fmaxf(fmaxf(p.x, p.y), fmaxf(p.z, p.w)));
  }
  #pragma unroll
  for (int o = 1; o < 64; o <<= 1) mx = fmaxf(mx, __shfl_xor(mx, o, 64));
  const float maxw = mx;
  const float kG   = G_DIFF / maxw;
  __syncthreads();

  // ---- 9-step branch-free MFMA loop (wave = k-slice of 288 = 72 j) ----
  const unsigned short* Ap = Ub + (size_t)(b0 + la) * KP4 + wv * 288 + kg * 8;
  const int jb = wv * 72 + kg * 2;
  f32x4 acc0 = {0.f, 0.f, 0.f, 0.f};
  f32x4 acc1 = {0.f, 0.f, 0.f, 0.f};
  #pragma unroll 3
  for (int ks = 0; ks < 9; ++ks) {
    const short8 a = *(const short8*)(Ap + ks * 32);
    const int j0 = jb + ks * 8;                // this lane's two j's: j0, j0+1
    const float w0a = bf2f(panel[j0 * 32 + la]);
    const float w0b = bf2f(panel[(j0 + 1) * 32 + la]);
    const float w1a = bf2f(panel[j0 * 32 + 16 + la]);
    const float w1b = bf2f(panel[(j0 + 1) * 32 + 16 + la]);
    float a1, a2, a3, b1, b2, b3, c1, c2, c3, d1, d2, d3;
    coeff3f(kG * w0a, a1, a2, a3);
    coeff3f(kG * w0b, b1, b2, b3);
    coeff3f(kG * w1a, c1, c2, c3);
    coeff3f(kG * w1b, d1, d2, d3);
    union { __hip_bfloat162 h[4]; short8 s; } bf0, bf1;
    bf0.h[0] = __float22bfloat162_rn(make_float2(a1, a2));
    bf0.h[1] = __float22bfloat162_rn(make_float2(a3, 0.f));
    bf0.h[2] = __float22bfloat162_rn(make_float2(b1, b2));
    bf0.h[3] = __float22bfloat162_rn(make_float2(b3, 0.f));
    bf1.h[0] = __float22bfloat162_rn(make_float2(c1, c2));
    bf1.h[1] = __float22bfloat162_rn(make_float2(c3, 0.f));
    bf1.h[2] = __float22bfloat162_rn(make_float2(d1, d2));
    bf1.h[3] = __float22bfloat162_rn(make_float2(d3, 0.f));
    acc0 = __builtin_amdgcn_mfma_f32_16x16x32_bf16(a, bf0.s, acc0, 0, 0, 0);
    acc1 = __builtin_amdgcn_mfma_f32_16x16x32_bf16(a, bf1.s, acc1, 0, 0, 0);
  }

  // ---- cross-wave K-reduce (P aliases the panel) + fused scale ----
  float* P = (float*)panel;                    // 32 KB < 72 KB, after barrier
  __syncthreads();                             // all waves done reading panel
  *(float4*)&P[wv * 512 + lane * 4]       = make_float4(acc0[0], acc0[1], acc0[2], acc0[3]);
  *(float4*)&P[wv * 512 + 256 + lane * 4] = make_float4(acc1[0], acc1[1], acc1[2], acc1[3]);
  __syncthreads();
  if (t < 512) {
    float s = 0.f;
    #pragma unroll
    for (int ww = 0; ww < 16; ++ww) s += P[ww * 512 + t];
    const int frag = t >> 8, f = t & 255;
    const int l2 = f >> 2, ai = f & 3;         // D: col = lane&15, row = kg*4+r
    const int row = b0 + ((l2 >> 4) << 2) + ai;
    const int col = n0 + frag * 16 + (l2 & 15);
    out[(size_t)row * 1024 + col] = s * (maxw * (1.0f / (K_V_C * G_DIFF)));
  }
}

// ---------------------------------------------------------------------------
// Fallback (tiny ws): atomic-based path, needs only 4 bytes of ws.
// ---------------------------------------------------------------------------
__global__ __launch_bounds__(256) void maxabs_atomic_kernel(
    const float* __restrict__ w, const float* __restrict__ b,
    unsigned int* __restrict__ wsmax) {
  const int NW4 = 262144, NB4 = 256;
  float m = 0.f;
  for (int i = blockIdx.x * blockDim.x + threadIdx.x; i < NW4 + NB4;
       i += gridDim.x * blockDim.x) {
    float4 v = (i < NW4) ? ((const float4*)w)[i] : ((const float4*)b)[i - NW4];
    m = fmaxf(m, fmaxf(fmaxf(fabsf(v.x), fabsf(v.y)),
                       fmaxf(fabsf(v.z), fabsf(v.w))));
  }
  #pragma unroll
  for (int o = 32; o > 0; o >>= 1) m = fmaxf(m, __shfl_down(m, o, 64));
  __shared__ float red[4];
  if ((threadIdx.x & 63) == 0) red[threadIdx.x >> 6] = m;
  __syncthreads();
  if (threadIdx.x == 0)
    atomicMax(wsmax, __float_as_uint(fmaxf(fmaxf(red[0], red[1]),
                                           fmaxf(red[2], red[3]))));
}

__global__ __launch_bounds__(256) void memristor_atomic_kernel(
    const float* __restrict__ x, const float* __restrict__ w,
    const float* __restrict__ bias, const unsigned int* __restrict__ wsmax,
    float* __restrict__ out) {
  __shared__ float4 U[2048];
  const int tid = threadIdx.x;
  const float maxw  = __uint_as_float(*wsmax);
  const float kG    = G_DIFF / maxw;
  const float scale = maxw * (1.0f / (K_V_C * G_DIFF));
  const int mq = tid & 15, bg = tid >> 4;
  const int m0 = blockIdx.x * 64 + mq * 4;
  const int swz = bg & 7;
  float acc[4][8];
  #pragma unroll
  for (int a = 0; a < 4; ++a)
    #pragma unroll
    for (int c = 0; c < 8; ++c) acc[a][c] = 0.f;
  for (int sc = blockIdx.y; sc < 65; sc += 16) {
    const int j0 = sc * 16;
    const int nj = min(16, 1025 - j0);
    __syncthreads();
    #pragma unroll
    for (int k = 0; k < 8; ++k) {
      const int e = k * 256 + tid;
      const int jl = e & 15, b = e >> 4;
      const int jg = j0 + jl;
      if (jg <= 1024) {
        const float v = (jg < 1024) ? K_V_C * x[b * 1024 + jg] : K_V_C;
        float u1, u2, u3;
        interp3(v, u1, u2, u3);
        U[b * 16 + (jl ^ ((b >> 3) & 7))] = make_float4(0.f, u1, u2, u3);
      }
    }
    __syncthreads();
    for (int jl = 0; jl < nj; ++jl) {
      const int jg = j0 + jl;
      const float4 wv = (jg < 1024) ? *(const float4*)(w + jg * 1024 + m0)
                                    : *(const float4*)(bias + m0);
      const float warr[4] = {wv.x, wv.y, wv.z, wv.w};
      float c1[4], c2[4], c3[4];
      #pragma unroll
      for (int mi = 0; mi < 4; ++mi) coeff3(kG * warr[mi], c1[mi], c2[mi], c3[mi]);
      const int base = bg * 128 + (jl ^ swz);
      #pragma unroll
      for (int bb = 0; bb < 8; ++bb) {
        const float4 u = U[base + bb * 16];
        #pragma unroll
        for (int mi = 0; mi < 4; ++mi)
          acc[mi][bb] = fmaf(c1[mi], u.y, fmaf(c2[mi], u.z, fmaf(c3[mi], u.w, acc[mi][bb])));
      }
    }
  }
  #pragma unroll
  for (int bb = 0; bb < 8; ++bb) {
    const int b = bg * 8 + bb;
    #pragma unroll
    for (int mi = 0; mi < 4; ++mi)
      atomicAdd(&out[b * 1024 + m0 + mi], acc[mi][bb] * scale);
  }
}

// ---------------------------------------------------------------------------
extern "C" void kernel_launch(void* const* d_in, const int* in_sizes, int n_in,
                              void* d_out, int out_size, void* d_ws, size_t ws_size,
                              hipStream_t stream) {
  const float* x = (const float*)d_in[0];   // (128, 1024)
  const float* w = (const float*)d_in[1];   // (1024, 1024)
  const float* b = (const float*)d_in[2];   // (1024,)
  float* out = (float*)d_out;               // (128, 1024) fp32

  float*          partials = (float*)((char*)d_ws + 128);        // 1024 f32
  unsigned short* Ub = (unsigned short*)((char*)d_ws + 8192);    // 1,179,648 B
  const size_t need = 8192 + (size_t)128 * KP4 * 2;              // ~1.13 MB

  if (ws_size >= need) {
    prep1_kernel<<<1168, 256, 0, stream>>>(x, w, b, partials, Ub);
    fusedgemm_kernel<<<256, 1024, 0, stream>>>(w, b, partials, Ub, out);
  } else {                                 // fallback: tiny ws, atomic path
    unsigned int* wsmax = (unsigned int*)d_ws;
    hipMemsetAsync(wsmax, 0, 4, stream);
    maxabs_atomic_kernel<<<256, 256, 0, stream>>>(w, b, wsmax);
    hipMemsetAsync(out, 0, (size_t)out_size * sizeof(float), stream);
    dim3 grid(16, 16);
    memristor_atomic_kernel<<<grid, 256, 0, stream>>>(x, w, b, wsmax, out);
  }
}